// Round 11
// baseline (390.527 us; speedup 1.0000x reference)
//
#include <hip/hip_runtime.h>

#define NIN 32
#define NU  128
#define RPB 4            // batch rows per block (R11: 8->4 for occupancy)
#define NQ  4            // i-range quarters (threads per j)
#define UNFOLDS 6
#define LOG2E 1.44269504088896340736f
#define TBL_N 4096       // sigmoid table entries over t in [-16, 16)
#define TBL_SCALE 128.0f // entries per unit t
#define TBL_OFF 2048.5f  // center offset + 0.5 for round-to-nearest via trunc

typedef float float4v __attribute__((ext_vector_type(4)));
typedef float float2v __attribute__((ext_vector_type(2)));
typedef __fp16 half2v __attribute__((ext_vector_type(2)));

#define SPN (NIN * NU)   // 4096 sensory synapses
#define RPN (NU * NU)    // 16384 recurrent synapses

// ---- prologue: pack params in BOTH spaces ----
__global__ void pack_params(const float* __restrict__ mu,
                            const float* __restrict__ sig,
                            const float* __restrict__ W,
                            const float* __restrict__ erev,
                            float4v* __restrict__ out_e,
                            float4v* __restrict__ out_t, int n) {
    int idx = blockIdx.x * blockDim.x + threadIdx.x;
    if (idx < n) {
        float sg = sig[idx];
        float s2 = -LOG2E * sg;
        float sm2 = -s2 * mu[idx];
        float Wv = W[idx];
        float We = Wv * erev[idx];
        out_e[idx] = (float4v){s2, sm2, We, Wv};
        out_t[idx] = (float4v){TBL_SCALE * s2,
                               __builtin_fmaf(TBL_SCALE, sm2, TBL_OFF), We, Wv};
    }
}

// ---- VOP3P packed-f32 primitives (op_sel broadcasts, no movs) ----
// t01 = (pxy.x*v01.x + pxy.y, pxy.x*v01.y + pxy.y)
#define PK_T(t01, pxy, v01)                                                    \
    asm("v_pk_fma_f32 %0, %1, %2, %1 op_sel:[0,0,1] op_sel_hi:[0,1,1]"         \
        : "=v"(t01) : "v"(pxy), "v"(v01))

// n01 += (We,We)*s01 ; d01 += (Wv,Wv)*s01   with pzw = (We, Wv)
#define PK_ACC(n01, d01, pzw, s01)                                             \
    asm("v_pk_fma_f32 %0, %2, %3, %0 op_sel:[0,0,0] op_sel_hi:[0,1,1]\n\t"     \
        "v_pk_fma_f32 %1, %2, %3, %1 op_sel:[1,0,0] op_sel_hi:[1,1,1]"         \
        : "+v"(n01), "+v"(d01) : "v"(pzw), "v"(s01))

// exp2 row-pair: packed t, scalar sigmoid interior (pair-shared rcp), packed accum
#define EVAL_EXP_PAIR(pxy, pzw, v01, n01, d01)                                 \
    {                                                                          \
        float2v t01; PK_T(t01, pxy, v01);                                      \
        float e0 = __builtin_amdgcn_exp2f(t01.x);                              \
        float e1 = __builtin_amdgcn_exp2f(t01.y);                              \
        float a1 = 1.0f + e1;                                                  \
        float P  = __builtin_fmaf(e0, a1, a1);                                 \
        float rq = __builtin_amdgcn_rcpf(P);                                   \
        float2v s01 = {rq * a1, __builtin_fmaf(rq, e0, rq)};                   \
        PK_ACC(n01, d01, pzw, s01);                                            \
    }

// table row-pair: packed addr fma, scalar clamp+cvt+gather, packed accum
#define EVAL_TBL_PAIR(pxy, pzw, v01, n01, d01)                                 \
    {                                                                          \
        float2v t01; PK_T(t01, pxy, v01);                                      \
        float a0 = __builtin_amdgcn_fmed3f(t01.x, 0.0f, (float)(TBL_N - 1));   \
        float a1 = __builtin_amdgcn_fmed3f(t01.y, 0.0f, (float)(TBL_N - 1));   \
        float2v s01 = {tbl[(unsigned)a0], tbl[(unsigned)a1]};                  \
        PK_ACC(n01, d01, pzw, s01);                                            \
    }

// One i-row: 4 batch-row evals (2 packed pairs) against param vector p.
template <bool USE_TBL>
__device__ __forceinline__ void eval_i(const float4v p,
                                       const float* __restrict__ vsrc, int i,
                                       const float* __restrict__ tbl,
                                       float2v& n01, float2v& n23,
                                       float2v& d01, float2v& d23) {
    float4v va = *(const float4v*)&vsrc[i * RPB];
    float2v pxy = __builtin_shufflevector(p, p, 0, 1);
    float2v pzw = __builtin_shufflevector(p, p, 2, 3);
    float2v va01 = __builtin_shufflevector(va, va, 0, 1);
    float2v va23 = __builtin_shufflevector(va, va, 2, 3);
    if constexpr (USE_TBL) {
        EVAL_TBL_PAIR(pxy, pzw, va01, n01, d01);
        EVAL_TBL_PAIR(pxy, pzw, va23, n23, d23);
    } else {
        EVAL_EXP_PAIR(pxy, pzw, va01, n01, d01);
        EVAL_EXP_PAIR(pxy, pzw, va23, n23, d23);
    }
}

// Range eval with compile-time bounds + 1-deep param prefetch.
// pb already includes +j.
template <int LO, int HI, bool USE_TBL>
__device__ __forceinline__ void eval_range(const float4v* __restrict__ pb,
                                           const float* __restrict__ vsrc,
                                           const float* __restrict__ tbl,
                                           float2v& n01, float2v& n23,
                                           float2v& d01, float2v& d23) {
    const float4v* pp = pb + LO * NU;
    float4v p = pp[0];
    for (int i = LO; i < HI - 1; ++i) {
        pp += NU;
        float4v pn = pp[0];              // issue next-iter load before body
        eval_i<USE_TBL>(p, vsrc, i, tbl, n01, n23, d01, d23);
        p = pn;
    }
    eval_i<USE_TBL>(p, vsrc, HI - 1, tbl, n01, n23, d01, d23);
}

#define ACC_DECL                                                               \
    float2v n01 = {0.f, 0.f}, n23 = {0.f, 0.f},                                \
            d01 = {0.f, 0.f}, d23 = {0.f, 0.f}

#define ACC_ARGS n01, n23, d01, d23

#define PUB(r, nv, dv)                                                         \
    sm.prt[r][q][j] = __builtin_bit_cast(unsigned,                             \
                          __builtin_amdgcn_cvt_pkrtz((nv), (dv)))

// R11: RPB 8->4 on the VERIFIED R2 skeleton (same reduction/barrier/union
// structure, same 27/37 split, same f16 publish path -> bitwise-identical
// accumulation order per row). Effects: 8 accumulators instead of 16 (fits
// the 32-VGPR budget WITHOUT R2's ~10-dword spills), LDS 40960->28672 B,
// so residency = wave-cap: 4 blocks x 8 waves = 32 waves/CU = full
// occupancy (was ~65%). Work conserved: 2048 blocks x half work. Params
// (640 KB) stay L2-resident at 2x read rate. Each thread owns ONE row (q).
__global__ __launch_bounds__(512, 8)
void wormnet_main(const float* __restrict__ inputs,   // [B,32]
                  const float* __restrict__ state,    // [B,128]
                  const float4v* __restrict__ spe, const float4v* __restrict__ spt,
                  const float4v* __restrict__ rpe, const float4v* __restrict__ rpt,
                  const float* __restrict__ vleak,
                  const float* __restrict__ gleak,
                  const float* __restrict__ cm_t,
                  const float* __restrict__ in_w, const float* __restrict__ in_b,
                  const float* __restrict__ out_w, const float* __restrict__ out_b,
                  float* __restrict__ out_y,          // [B]
                  float* __restrict__ out_v)          // [B,128]
{
    __shared__ __align__(16) float tbl[TBL_N];        // 16 KB
    __shared__ __align__(16) float vs[NU * RPB];      //  2 KB  vs[i*4 + r]
    __shared__ __align__(16) union {
        float xs[NIN * RPB];                          //  (512 B used)
        unsigned prt[RPB][NQ][NU];                    //  8 KB  half2(num,den)
    } sm;
    __shared__ unsigned wsum[RPB][NU];                //  2 KB  half2 sensory
                                                      // total 28672 B

    const int tid  = threadIdx.x;
    const int j    = tid & (NU - 1);
    const int q    = tid >> 7;            // 0..3, wave-uniform; owner row = q
    const int base = blockIdx.x * RPB;

    // build sigmoid table: s(t_k) = 1/(1+2^t), t_k = (k - 2048)/128
    #pragma unroll
    for (int k = tid; k < TBL_N; k += 512) {
        float t = (float)(k - TBL_N / 2) * (1.0f / TBL_SCALE);
        tbl[k] = __builtin_amdgcn_rcpf(1.0f + __builtin_amdgcn_exp2f(t));
    }

    // stage x = inputs*in_w + in_b (128 values; first 128 threads)
    if (tid < NIN * RPB) {
        int i = tid & (NIN - 1);
        int r = tid >> 5;                 // 0..3
        sm.xs[i * RPB + r] = inputs[(base + r) * NIN + i] * in_w[i] + in_b[i];
    }
    // stage initial v (512 values, 1 per thread, coalesced over i)
    {
        int i = tid & (NU - 1);
        int r = tid >> 7;
        vs[i * RPB + r] = state[(base + r) * NU + i];
    }
    // this thread's own row (q) at unit j
    float vold = state[(base + q) * NU + j];
    __syncthreads();

    // ---- sensory phase: partials -> prt -> reduce to wsum (once) ----
    {
        ACC_DECL;
        switch (q) {
        case 0:  eval_range<0,  7,  false>(spe + j, sm.xs, tbl, ACC_ARGS); break;
        case 1:  eval_range<7,  14, false>(spe + j, sm.xs, tbl, ACC_ARGS); break;
        case 2:  eval_range<14, 23, true >(spt + j, sm.xs, tbl, ACC_ARGS); break;
        default: eval_range<23, 32, true >(spt + j, sm.xs, tbl, ACC_ARGS); break;
        }
        __syncthreads();   // all xs reads done before prt overwrite
        PUB(0, n01.x, d01.x); PUB(1, n01.y, d01.y);
        PUB(2, n23.x, d23.x); PUB(3, n23.y, d23.y);
        __syncthreads();
        // each thread reduces 1 (r,j') pair into wsum
        {
            int rr = tid >> 7, jj = tid & (NU - 1);
            float tn = 0.0f, td = 0.0f;
            #pragma unroll
            for (int qq = 0; qq < NQ; ++qq) {
                half2v h = __builtin_bit_cast(half2v, sm.prt[rr][qq][jj]);
                tn += (float)h[0];
                td += (float)h[1];
            }
            wsum[rr][jj] = __builtin_bit_cast(unsigned,
                               __builtin_amdgcn_cvt_pkrtz(tn, td));
        }
        __syncthreads();   // wsum ready; prt reads done before unfold publish
    }

    // per-unit constants
    const float cm = cm_t[j];
    const float gl = gleak[j];
    const float glvl = gl * vleak[j];
    const float cg = cm + gl;

    // ---- 6 semi-implicit unfolds ----
    for (int u = 0; u < UNFOLDS; ++u) {
        ACC_DECL;
        switch (q) {
        case 0:  eval_range<0,  27,  false>(rpe + j, vs, tbl, ACC_ARGS); break;
        case 1:  eval_range<27, 54,  false>(rpe + j, vs, tbl, ACC_ARGS); break;
        case 2:  eval_range<54, 91,  true >(rpt + j, vs, tbl, ACC_ARGS); break;
        default: eval_range<91, 128, true >(rpt + j, vs, tbl, ACC_ARGS); break;
        }

        // publish partials as packed half2 (coalesced over j, conflict-free)
        PUB(0, n01.x, d01.x); PUB(1, n01.y, d01.y);
        PUB(2, n23.x, d23.x); PUB(3, n23.y, d23.y);
        __syncthreads();

        // update this thread's owner row q (sensory from wsum)
        {
            half2v hs = __builtin_bit_cast(half2v, wsum[q][j]);
            float tn = (float)hs[0], td = (float)hs[1];
            #pragma unroll
            for (int qq = 0; qq < NQ; ++qq) {
                half2v h = __builtin_bit_cast(half2v, sm.prt[q][qq][j]);
                tn += (float)h[0];
                td += (float)h[1];
            }
            float vn = (__builtin_fmaf(cm, vold, glvl) + tn)
                       * __builtin_amdgcn_rcpf(cg + td);
            vold = vn;
            vs[j * RPB + q] = vn;
        }
        __syncthreads();
    }

    // ---- epilogue: thread (j,q) writes its row (coalesced over j) ----
    out_v[(base + q) * NU + j] = vold;
    if (j == 0) {
        out_y[base + q] = __builtin_fmaf(vold, out_w[0], out_b[0]);
    }
}

extern "C" void kernel_launch(void* const* d_in, const int* in_sizes, int n_in,
                              void* d_out, int out_size, void* d_ws, size_t ws_size,
                              hipStream_t stream) {
    const float* inputs  = (const float*)d_in[0];
    const float* state   = (const float*)d_in[1];
    const float* smu     = (const float*)d_in[2];
    const float* ssig    = (const float*)d_in[3];
    const float* sW      = (const float*)d_in[4];
    const float* serev   = (const float*)d_in[5];
    const float* rmu     = (const float*)d_in[6];
    const float* rsig    = (const float*)d_in[7];
    const float* rW      = (const float*)d_in[8];
    const float* rerev   = (const float*)d_in[9];
    const float* vleak   = (const float*)d_in[10];
    const float* gleak   = (const float*)d_in[11];
    const float* cm_t    = (const float*)d_in[12];
    const float* in_w    = (const float*)d_in[13];
    const float* in_b    = (const float*)d_in[14];
    const float* out_w   = (const float*)d_in[15];
    const float* out_b   = (const float*)d_in[16];

    const int batch = in_sizes[1] / NU;        // 8192
    float* out_y = (float*)d_out;              // [batch]
    float* out_v = (float*)d_out + batch;      // [batch,128]

    // workspace layout: spe, spt, rpe, rpt  (640 KB total)
    float4v* spe = (float4v*)d_ws;
    float4v* spt = spe + SPN;
    float4v* rpe = spt + SPN;
    float4v* rpt = rpe + RPN;

    hipLaunchKernelGGL(pack_params, dim3((SPN + 255) / 256), dim3(256), 0, stream,
                       smu, ssig, sW, serev, spe, spt, SPN);
    hipLaunchKernelGGL(pack_params, dim3((RPN + 255) / 256), dim3(256), 0, stream,
                       rmu, rsig, rW, rerev, rpe, rpt, RPN);

    dim3 grid(batch / RPB), block(NU * NQ);    // 2048 x 512
    hipLaunchKernelGGL(wormnet_main, grid, block, 0, stream,
                       inputs, state, spe, spt, rpe, rpt,
                       vleak, gleak, cm_t, in_w, in_b, out_w, out_b,
                       out_y, out_v);
}

// Round 13
// 244.308 us; speedup vs baseline: 1.5985x; 1.5985x over previous
//
#include <hip/hip_runtime.h>

#define NIN 32
#define NU  128
#define RPB 8            // batch rows per block
#define NQ  4            // i-range quarters (threads per j)
#define UNFOLDS 6
#define LOG2E 1.44269504088896340736f
#define TBL_N 4096       // sigmoid table entries over t in [-16, 16)
#define TBL_SCALE 128.0f // entries per unit t
#define TBL_OFF 2048.5f  // center offset + 0.5 for round-to-nearest via trunc

typedef float float4v __attribute__((ext_vector_type(4)));
typedef float float2v __attribute__((ext_vector_type(2)));
typedef __fp16 half2v __attribute__((ext_vector_type(2)));

#define SPN (NIN * NU)   // 4096 sensory synapses
#define RPN (NU * NU)    // 16384 recurrent synapses

// ---- prologue: pack params in BOTH spaces ----
__global__ void pack_params(const float* __restrict__ mu,
                            const float* __restrict__ sig,
                            const float* __restrict__ W,
                            const float* __restrict__ erev,
                            float4v* __restrict__ out_e,
                            float4v* __restrict__ out_t, int n) {
    int idx = blockIdx.x * blockDim.x + threadIdx.x;
    if (idx < n) {
        float sg = sig[idx];
        float s2 = -LOG2E * sg;
        float sm2 = -s2 * mu[idx];
        float Wv = W[idx];
        float We = Wv * erev[idx];
        out_e[idx] = (float4v){s2, sm2, We, Wv};
        out_t[idx] = (float4v){TBL_SCALE * s2,
                               __builtin_fmaf(TBL_SCALE, sm2, TBL_OFF), We, Wv};
    }
}

// ---- VOP3P packed-f32 primitives (op_sel broadcasts, no movs) ----
// t01 = (pxy.x*v01.x + pxy.y, pxy.x*v01.y + pxy.y)
#define PK_T(t01, pxy, v01)                                                    \
    asm("v_pk_fma_f32 %0, %1, %2, %1 op_sel:[0,0,1] op_sel_hi:[0,1,1]"         \
        : "=v"(t01) : "v"(pxy), "v"(v01))

// n01 += (We,We)*s01 ; d01 += (Wv,Wv)*s01   with pzw = (We, Wv)
#define PK_ACC(n01, d01, pzw, s01)                                             \
    asm("v_pk_fma_f32 %0, %2, %3, %0 op_sel:[0,0,0] op_sel_hi:[0,1,1]\n\t"     \
        "v_pk_fma_f32 %1, %2, %3, %1 op_sel:[1,0,0] op_sel_hi:[1,1,1]"         \
        : "+v"(n01), "+v"(d01) : "v"(pzw), "v"(s01))

// exp2 row-pair: packed t, scalar sigmoid interior (pair-shared rcp), packed accum
#define EVAL_EXP_PAIR(pxy, pzw, v01, n01, d01)                                 \
    {                                                                          \
        float2v t01; PK_T(t01, pxy, v01);                                      \
        float e0 = __builtin_amdgcn_exp2f(t01.x);                              \
        float e1 = __builtin_amdgcn_exp2f(t01.y);                              \
        float a1 = 1.0f + e1;                                                  \
        float P  = __builtin_fmaf(e0, a1, a1);                                 \
        float rq = __builtin_amdgcn_rcpf(P);                                   \
        float2v s01 = {rq * a1, __builtin_fmaf(rq, e0, rq)};                   \
        PK_ACC(n01, d01, pzw, s01);                                            \
    }

// table row-pair: packed addr fma, scalar clamp+cvt+gather, packed accum
#define EVAL_TBL_PAIR(pxy, pzw, v01, n01, d01)                                 \
    {                                                                          \
        float2v t01; PK_T(t01, pxy, v01);                                      \
        float a0 = __builtin_amdgcn_fmed3f(t01.x, 0.0f, (float)(TBL_N - 1));   \
        float a1 = __builtin_amdgcn_fmed3f(t01.y, 0.0f, (float)(TBL_N - 1));   \
        float2v s01 = {tbl[(unsigned)a0], tbl[(unsigned)a1]};                  \
        PK_ACC(n01, d01, pzw, s01);                                            \
    }

// One i-row: 8 batch-row evals (4 packed pairs) against param vector p.
template <bool USE_TBL>
__device__ __forceinline__ void eval_i(const float4v p,
                                       const float* __restrict__ vsrc, int i,
                                       const float* __restrict__ tbl,
                                       float2v& n01, float2v& n23,
                                       float2v& n45, float2v& n67,
                                       float2v& d01, float2v& d23,
                                       float2v& d45, float2v& d67) {
    float4v va = *(const float4v*)&vsrc[i * RPB];
    float4v vb = *(const float4v*)&vsrc[i * RPB + 4];
    float2v pxy = __builtin_shufflevector(p, p, 0, 1);
    float2v pzw = __builtin_shufflevector(p, p, 2, 3);
    float2v va01 = __builtin_shufflevector(va, va, 0, 1);
    float2v va23 = __builtin_shufflevector(va, va, 2, 3);
    float2v vb01 = __builtin_shufflevector(vb, vb, 0, 1);
    float2v vb23 = __builtin_shufflevector(vb, vb, 2, 3);
    if constexpr (USE_TBL) {
        EVAL_TBL_PAIR(pxy, pzw, va01, n01, d01);
        EVAL_TBL_PAIR(pxy, pzw, va23, n23, d23);
        EVAL_TBL_PAIR(pxy, pzw, vb01, n45, d45);
        EVAL_TBL_PAIR(pxy, pzw, vb23, n67, d67);
    } else {
        EVAL_EXP_PAIR(pxy, pzw, va01, n01, d01);
        EVAL_EXP_PAIR(pxy, pzw, va23, n23, d23);
        EVAL_EXP_PAIR(pxy, pzw, vb01, n45, d45);
        EVAL_EXP_PAIR(pxy, pzw, vb23, n67, d67);
    }
}

// Range eval with compile-time bounds + 1-deep param prefetch.
// pb already includes +j.
template <int LO, int HI, bool USE_TBL>
__device__ __forceinline__ void eval_range(const float4v* __restrict__ pb,
                                           const float* __restrict__ vsrc,
                                           const float* __restrict__ tbl,
                                           float2v& n01, float2v& n23,
                                           float2v& n45, float2v& n67,
                                           float2v& d01, float2v& d23,
                                           float2v& d45, float2v& d67) {
    const float4v* pp = pb + LO * NU;
    float4v p = pp[0];
    for (int i = LO; i < HI - 1; ++i) {
        pp += NU;
        float4v pn = pp[0];              // issue next-iter load before body
        eval_i<USE_TBL>(p, vsrc, i, tbl, n01, n23, n45, n67, d01, d23, d45, d67);
        p = pn;
    }
    eval_i<USE_TBL>(p, vsrc, HI - 1, tbl, n01, n23, n45, n67, d01, d23, d45, d67);
}

#define ACC_DECL                                                               \
    float2v n01 = {0.f, 0.f}, n23 = {0.f, 0.f}, n45 = {0.f, 0.f},              \
            n67 = {0.f, 0.f};                                                  \
    float2v d01 = {0.f, 0.f}, d23 = {0.f, 0.f}, d45 = {0.f, 0.f},              \
            d67 = {0.f, 0.f}

#define ACC_ARGS n01, n23, n45, n67, d01, d23, d45, d67

#define PUB(r, nv, dv)                                                         \
    sm.prt[r][q][j] = __builtin_bit_cast(unsigned,                             \
                          __builtin_amdgcn_cvt_pkrtz((nv), (dv)))

// block = 512: j = tid&127, q = tid>>7 (wave-uniform; selects i-range+method).
// i-range split per q: q0,q1 -> exp2; q2,q3 -> table.
// Recurrent: [0,27) [27,54) [54,91) [91,128)  <- measured balance optimum
// (R8: 21/43 = 183.2us, R9: 32/32 = 183.2us, this 27/37 = 177.7us).
// Sensory: [0,7) [7,14) [14,23) [23,32).
// VERIFIED R2 STRUCTURE — session best (177.7us kernel, passed 3x):
//   - launch_bounds(512,8): VGPR=32 budget. R6 measured VGPR=44 -> occupancy
//     65->40 (worse net); R11 measured RPB=4 at this budget -> 9x spill
//     explosion (327us). The ~10-dword/thread spill here is the cheapest
//     known allocation.
//   - f16 prt publish + wsum reduce through LDS: both removal attempts
//     (R7 q-packed relayout, R10 swizzle-butterfly) failed correctness.
__global__ __launch_bounds__(512, 8)
void wormnet_main(const float* __restrict__ inputs,   // [B,32]
                  const float* __restrict__ state,    // [B,128]
                  const float4v* __restrict__ spe, const float4v* __restrict__ spt,
                  const float4v* __restrict__ rpe, const float4v* __restrict__ rpt,
                  const float* __restrict__ vleak,
                  const float* __restrict__ gleak,
                  const float* __restrict__ cm_t,
                  const float* __restrict__ in_w, const float* __restrict__ in_b,
                  const float* __restrict__ out_w, const float* __restrict__ out_b,
                  float* __restrict__ out_y,          // [B]
                  float* __restrict__ out_v)          // [B,128]
{
    __shared__ __align__(16) float tbl[TBL_N];        // 16 KB
    __shared__ __align__(16) float vs[NU * RPB];      //  4 KB  vs[i*8 + r]
    __shared__ __align__(16) union {
        float xs[NIN * RPB];                          //  (1 KB used)
        unsigned prt[RPB][NQ][NU];                    // 16 KB  half2(num,den)
    } sm;
    __shared__ unsigned wsum[RPB][NU];                //  4 KB  half2 sensory

    const int tid  = threadIdx.x;
    const int j    = tid & (NU - 1);
    const int q    = tid >> 7;            // 0..3, wave-uniform
    const int u0   = q * 2;               // owner rows u0, u0+1
    const int base = blockIdx.x * RPB;

    // build sigmoid table: s(t_k) = 1/(1+2^t), t_k = (k - 2048)/128
    #pragma unroll
    for (int k = tid; k < TBL_N; k += 512) {
        float t = (float)(k - TBL_N / 2) * (1.0f / TBL_SCALE);
        tbl[k] = __builtin_amdgcn_rcpf(1.0f + __builtin_amdgcn_exp2f(t));
    }

    // stage x = inputs*in_w + in_b (256 values; first 256 threads)
    if (tid < NIN * RPB) {
        int i = tid & (NIN - 1);
        int r = tid >> 5;
        sm.xs[i * RPB + r] = inputs[(base + r) * NIN + i] * in_w[i] + in_b[i];
    }
    // stage initial v (1024 values, 2 per thread: owner rows, coalesced in j)
    float vold[2];
    #pragma unroll
    for (int k = 0; k < 2; ++k) {
        vold[k] = state[(base + u0 + k) * NU + j];
        vs[j * RPB + u0 + k] = vold[k];
    }
    __syncthreads();

    // ---- sensory phase: partials -> prt -> reduce to wsum (once) ----
    {
        ACC_DECL;
        switch (q) {
        case 0:  eval_range<0,  7,  false>(spe + j, sm.xs, tbl, ACC_ARGS); break;
        case 1:  eval_range<7,  14, false>(spe + j, sm.xs, tbl, ACC_ARGS); break;
        case 2:  eval_range<14, 23, true >(spt + j, sm.xs, tbl, ACC_ARGS); break;
        default: eval_range<23, 32, true >(spt + j, sm.xs, tbl, ACC_ARGS); break;
        }
        __syncthreads();   // all xs reads done before prt overwrite
        PUB(0, n01.x, d01.x); PUB(1, n01.y, d01.y);
        PUB(2, n23.x, d23.x); PUB(3, n23.y, d23.y);
        PUB(4, n45.x, d45.x); PUB(5, n45.y, d45.y);
        PUB(6, n67.x, d67.x); PUB(7, n67.y, d67.y);
        __syncthreads();
        // each thread reduces 2 (r,j') pairs into wsum
        #pragma unroll
        for (int k = 0; k < 2; ++k) {
            int m = 2 * tid + k;
            int rr = m >> 7, jj = m & (NU - 1);
            float tn = 0.0f, td = 0.0f;
            #pragma unroll
            for (int qq = 0; qq < NQ; ++qq) {
                half2v h = __builtin_bit_cast(half2v, sm.prt[rr][qq][jj]);
                tn += (float)h[0];
                td += (float)h[1];
            }
            wsum[rr][jj] = __builtin_bit_cast(unsigned,
                               __builtin_amdgcn_cvt_pkrtz(tn, td));
        }
        __syncthreads();   // wsum ready; prt reads done before unfold publish
    }

    // per-unit constants
    const float cm = cm_t[j];
    const float gl = gleak[j];
    const float glvl = gl * vleak[j];
    const float cg = cm + gl;

    // ---- 6 semi-implicit unfolds ----
    for (int u = 0; u < UNFOLDS; ++u) {
        ACC_DECL;
        switch (q) {
        case 0:  eval_range<0,  27,  false>(rpe + j, vs, tbl, ACC_ARGS); break;
        case 1:  eval_range<27, 54,  false>(rpe + j, vs, tbl, ACC_ARGS); break;
        case 2:  eval_range<54, 91,  true >(rpt + j, vs, tbl, ACC_ARGS); break;
        default: eval_range<91, 128, true >(rpt + j, vs, tbl, ACC_ARGS); break;
        }

        // publish partials as packed half2 (coalesced over j, conflict-free)
        PUB(0, n01.x, d01.x); PUB(1, n01.y, d01.y);
        PUB(2, n23.x, d23.x); PUB(3, n23.y, d23.y);
        PUB(4, n45.x, d45.x); PUB(5, n45.y, d45.y);
        PUB(6, n67.x, d67.x); PUB(7, n67.y, d67.y);
        __syncthreads();

        // update this thread's owner rows u0, u0+1 (sensory from wsum)
        #pragma unroll
        for (int k = 0; k < 2; ++k) {
            const int r = u0 + k;
            half2v hs = __builtin_bit_cast(half2v, wsum[r][j]);
            float tn = (float)hs[0], td = (float)hs[1];
            #pragma unroll
            for (int qq = 0; qq < NQ; ++qq) {
                half2v h = __builtin_bit_cast(half2v, sm.prt[r][qq][j]);
                tn += (float)h[0];
                td += (float)h[1];
            }
            float vn = (__builtin_fmaf(cm, vold[k], glvl) + tn)
                       * __builtin_amdgcn_rcpf(cg + td);
            vold[k] = vn;
            vs[j * RPB + r] = vn;
        }
        __syncthreads();
    }

    // ---- epilogue: thread (j,q) writes its 2 rows (coalesced over j) ----
    #pragma unroll
    for (int k = 0; k < 2; ++k) {
        out_v[(base + u0 + k) * NU + j] = vold[k];
    }
    if (j == 0) {
        const float ow = out_w[0], ob = out_b[0];
        #pragma unroll
        for (int k = 0; k < 2; ++k) {
            out_y[base + u0 + k] = __builtin_fmaf(vold[k], ow, ob);
        }
    }
}

extern "C" void kernel_launch(void* const* d_in, const int* in_sizes, int n_in,
                              void* d_out, int out_size, void* d_ws, size_t ws_size,
                              hipStream_t stream) {
    const float* inputs  = (const float*)d_in[0];
    const float* state   = (const float*)d_in[1];
    const float* smu     = (const float*)d_in[2];
    const float* ssig    = (const float*)d_in[3];
    const float* sW      = (const float*)d_in[4];
    const float* serev   = (const float*)d_in[5];
    const float* rmu     = (const float*)d_in[6];
    const float* rsig    = (const float*)d_in[7];
    const float* rW      = (const float*)d_in[8];
    const float* rerev   = (const float*)d_in[9];
    const float* vleak   = (const float*)d_in[10];
    const float* gleak   = (const float*)d_in[11];
    const float* cm_t    = (const float*)d_in[12];
    const float* in_w    = (const float*)d_in[13];
    const float* in_b    = (const float*)d_in[14];
    const float* out_w   = (const float*)d_in[15];
    const float* out_b   = (const float*)d_in[16];

    const int batch = in_sizes[1] / NU;        // 8192
    float* out_y = (float*)d_out;              // [batch]
    float* out_v = (float*)d_out + batch;      // [batch,128]

    // workspace layout: spe, spt, rpe, rpt  (640 KB total)
    float4v* spe = (float4v*)d_ws;
    float4v* spt = spe + SPN;
    float4v* rpe = spt + SPN;
    float4v* rpt = rpe + RPN;

    hipLaunchKernelGGL(pack_params, dim3((SPN + 255) / 256), dim3(256), 0, stream,
                       smu, ssig, sW, serev, spe, spt, SPN);
    hipLaunchKernelGGL(pack_params, dim3((RPN + 255) / 256), dim3(256), 0, stream,
                       rmu, rsig, rW, rerev, rpe, rpt, RPN);

    dim3 grid(batch / RPB), block(NU * NQ);    // 1024 x 512
    hipLaunchKernelGGL(wormnet_main, grid, block, 0, stream,
                       inputs, state, spe, spt, rpe, rpt,
                       vleak, gleak, cm_t, in_w, in_b, out_w, out_b,
                       out_y, out_v);
}